// Round 5
// baseline (109.542 us; speedup 1.0000x reference)
//
#include <hip/hip_runtime.h>
#include <stdint.h>

// RBF layer: out[b,c] = exp(-gamma * sqrt(max(||x_b||^2 - 2 x_b.c_c + ||c_c||^2, 0)))
// B=16384, D=1024, C=2048 (fp32 in/out).
// bf16 MFMA GEMM, 256x256 tile, BK=32, 3-buffer LDS ring, counted vmcnt(4),
// and a software-pipelined phase schedule: fragment ds_reads issued ONE PHASE
// AHEAD, waited with COUNTED lgkmcnt(4/8) (+sched_barrier, rule #18) so LDS
// latency hides under the previous MFMA cluster. setprio around MFMA clusters.
// Slot-rotation LDS swizzle via pre-swizzled global source (0 conflicts,
// verified r2-r4). fp32 row-norms from original data; fused sqrt/exp epilogue.

typedef __attribute__((ext_vector_type(8))) short bf16x8;
typedef __attribute__((ext_vector_type(4))) float f32x4;

#define BM 256
#define BN 256
#define BK 32

__device__ __forceinline__ unsigned short f2bf(float f) {
  union { float f; unsigned int u; } c; c.f = f;
  unsigned int u = c.u;
  unsigned int r = (u + 0x7fffu + ((u >> 16) & 1u)) >> 16;  // RNE
  return (unsigned short)r;
}

// One block per row: fp32 -> bf16 convert + fp32 sum-of-squares.
__global__ __launch_bounds__(256) void prep_rows(
    const float* __restrict__ in, unsigned short* __restrict__ ob,
    float* __restrict__ norm, int K) {
  int row = blockIdx.x;
  const float4* rp = (const float4*)(in + (size_t)row * K);
  ushort4* op = (ushort4*)(ob + (size_t)row * K);
  float s = 0.f;
  for (int i = threadIdx.x; i < (K >> 2); i += blockDim.x) {
    float4 v = rp[i];
    s += v.x * v.x + v.y * v.y + v.z * v.z + v.w * v.w;
    ushort4 u;
    u.x = f2bf(v.x); u.y = f2bf(v.y); u.z = f2bf(v.z); u.w = f2bf(v.w);
    op[i] = u;
  }
  for (int off = 32; off > 0; off >>= 1) s += __shfl_down(s, off, 64);
  __shared__ float partial[4];
  int lane = threadIdx.x & 63, wv = threadIdx.x >> 6;
  if (lane == 0) partial[wv] = s;
  __syncthreads();
  if (threadIdx.x == 0) {
    float t = 0.f;
    int nw = (blockDim.x + 63) >> 6;
    for (int w = 0; w < nw; ++w) t += partial[w];
    norm[row] = t;
  }
}

#define GLDS(gptr, lptr)                                                      \
  __builtin_amdgcn_global_load_lds(                                           \
      (const __attribute__((address_space(1))) unsigned int*)(gptr),          \
      (__attribute__((address_space(3))) unsigned int*)(lptr), 16, 0, 0)

// Inline-asm LDS read: byte-address VGPR + compile-time immediate offset.
#define DSR(dst, addr, imm)                                                   \
  asm volatile("ds_read_b128 %0, %1 offset:%c2"                              \
               : "=v"(dst) : "v"(addr), "i"(imm))

// Counted DS wait + scheduling fence (rule #18).
#define WAIT_LGKM(n)                                                          \
  do {                                                                        \
    asm volatile("s_waitcnt lgkmcnt(" #n ")" ::: "memory");                   \
    __builtin_amdgcn_sched_barrier(0);                                        \
  } while (0)

#define MFMA(a, b, c) __builtin_amdgcn_mfma_f32_16x16x32_bf16((a), (b), (c), 0, 0, 0)

// 256x256 bf16 GEMM, counted-vmcnt 3-buffer ring, read-ahead phases + fused
// RBF epilogue. A: [M][K] bf16 row-major (x). Bm: [N][K] bf16 (centers).
__global__ __launch_bounds__(512, 2) void rbf_gemm(
    const unsigned short* __restrict__ A, const unsigned short* __restrict__ Bm,
    const float* __restrict__ x2, const float* __restrict__ c2,
    const float* __restrict__ gamma, float* __restrict__ out,
    int M, int N, int K) {
  // 3 buffers x 32KB: per buffer A-tile 16KB (256x32 bf16) then B-tile 16KB.
  // Physical 16B slot p of row r holds logical slot l where p=(l+(r>>1))&3.
  __shared__ __align__(16) unsigned short lds[3 * 16384];

  int nbn = N / BN;
  int nwg = (M / BM) * nbn;
  int bid = blockIdx.x;
  int wg = bid;
  if ((nwg & 7) == 0) {  // XCD-aware swizzle (bijective: nwg % 8 == 0)
    int cpx = nwg >> 3;
    wg = (bid & 7) * cpx + (bid >> 3);
  }
  int bm = wg / nbn, bn = wg % nbn;

  int tid = threadIdx.x;
  int lane = tid & 63, wv = tid >> 6;
  int wm = wv >> 1;   // 0..3 : wave row (64 rows each)
  int wn = wv & 1;    // 0..1 : wave col (128 cols each)
  int l15 = lane & 15, l4 = lane >> 4;

  // ---- staging map: each gload inst covers 128 rows x 64B (8KB) ----
  int lsw = ((tid & 3) - (tid >> 3)) & 3;  // pre-swizzled logical slot
  const unsigned short* AgT =
      A + (size_t)bm * BM * K + (size_t)(tid >> 2) * K + lsw * 8;
  const unsigned short* BgT =
      Bm + (size_t)bn * BN * K + (size_t)(tid >> 2) * K + lsw * 8;
  size_t rstep = (size_t)128 * K;

  // ---- fragment read map (contiguous 1KB per wave -> conflict-free) ----
  int pc = (l4 + (l15 >> 1)) & 3;                       // phys slot this lane
  unsigned aByte = (unsigned)((wm * 64 + l15) * 64 + pc * 16);
  unsigned bByte = (unsigned)(16384 + (wn * 128 + l15) * 64 + pc * 16);
  unsigned ldsBase =
      (unsigned)(size_t)(const __attribute__((address_space(3))) void*)&lds[0];

  f32x4 acc[4][8];
#pragma unroll
  for (int m = 0; m < 4; ++m)
#pragma unroll
    for (int n = 0; n < 8; ++n) acc[m][n] = (f32x4){0.f, 0.f, 0.f, 0.f};

  int nt = K / BK;

  // ---- prologue: stage tiles 0,1 into buffers 0,1 ----
#pragma unroll
  for (int tt = 0; tt < 2; ++tt) {
    unsigned short* base = lds + tt * 16384;
    GLDS(AgT + (size_t)tt * BK, base + tid * 8);
    GLDS(AgT + rstep + (size_t)tt * BK, base + 4096 + tid * 8);
    GLDS(BgT + (size_t)tt * BK, base + 8192 + tid * 8);
    GLDS(BgT + rstep + (size_t)tt * BK, base + 12288 + tid * 8);
  }
  asm volatile("s_waitcnt vmcnt(4)" ::: "memory");  // tile 0 resident
  __builtin_amdgcn_s_barrier();

  // ---- pre-issue phase-0 reads of tile 0: A(m0-3) + B(n0-3), 8 reads ----
  bf16x8 aC0, aC1, aC2, aC3, bC0, bC1, bC2, bC3;
  {
    unsigned aAd = ldsBase + aByte;
    unsigned bAd = ldsBase + bByte;
    DSR(aC0, aAd, 0);    DSR(aC1, aAd, 1024);
    DSR(aC2, aAd, 2048); DSR(aC3, aAd, 3072);
    DSR(bC0, bAd, 0);    DSR(bC1, bAd, 1024);
    DSR(bC2, bAd, 2048); DSR(bC3, bAd, 3072);
  }

  int rb = 0;
  for (int t = 0; t < nt; ++t) {
    unsigned bufOff = (unsigned)rb * 32768u;
    int rbN = rb + 1; if (rbN == 3) rbN = 0;       // buffer of tile t+1
    int sbi = rb + 2; if (sbi >= 3) sbi -= 3;      // stage target (t+2)
    unsigned short* bufS = lds + sbi * 16384;
    size_t ktS = (size_t)(t + 2) * BK;
    bool doStage = (t + 2 < nt);
    unsigned bAdC = ldsBase + bufOff + bByte;

    // ===== phase 0: issue B(n4-7)(t) reads; stage A(t+2); MFMA A x B(n0-3)
    bf16x8 b4, b5, b6, b7;
    DSR(b4, bAdC, 4096); DSR(b5, bAdC, 5120);
    DSR(b6, bAdC, 6144); DSR(b7, bAdC, 7168);
    if (doStage) {
      GLDS(AgT + ktS, bufS + tid * 8);
      GLDS(AgT + rstep + ktS, bufS + 4096 + tid * 8);
    }
    __builtin_amdgcn_s_barrier();
    WAIT_LGKM(4);  // waits the 8 reads issued last phase (A + B(n0-3) of t)
    __builtin_amdgcn_s_setprio(1);
    acc[0][0] = MFMA(aC0, bC0, acc[0][0]);
    acc[0][1] = MFMA(aC0, bC1, acc[0][1]);
    acc[0][2] = MFMA(aC0, bC2, acc[0][2]);
    acc[0][3] = MFMA(aC0, bC3, acc[0][3]);
    acc[1][0] = MFMA(aC1, bC0, acc[1][0]);
    acc[1][1] = MFMA(aC1, bC1, acc[1][1]);
    acc[1][2] = MFMA(aC1, bC2, acc[1][2]);
    acc[1][3] = MFMA(aC1, bC3, acc[1][3]);
    acc[2][0] = MFMA(aC2, bC0, acc[2][0]);
    acc[2][1] = MFMA(aC2, bC1, acc[2][1]);
    acc[2][2] = MFMA(aC2, bC2, acc[2][2]);
    acc[2][3] = MFMA(aC2, bC3, acc[2][3]);
    acc[3][0] = MFMA(aC3, bC0, acc[3][0]);
    acc[3][1] = MFMA(aC3, bC1, acc[3][1]);
    acc[3][2] = MFMA(aC3, bC2, acc[3][2]);
    acc[3][3] = MFMA(aC3, bC3, acc[3][3]);
    __builtin_amdgcn_s_setprio(0);
    __builtin_amdgcn_s_barrier();

    // ===== phase 1: issue A+B(n0-3)(t+1) reads; stage B(t+2); MFMA A x B(n4-7)
    // Read target buf[(t+1)%3]: resident (staged 2 tiles ago); not a stage
    // target until tile t+1 stages (t+3)%3 == t%3 != (t+1)%3 -> no WAR.
    bf16x8 aN0, aN1, aN2, aN3, bN0, bN1, bN2, bN3;
    {
      int tn = (t + 1 < nt) ? rbN : rb;  // tail guard: redundant safe reads
      unsigned aAdN = ldsBase + (unsigned)tn * 32768u + aByte;
      unsigned bAdN = ldsBase + (unsigned)tn * 32768u + bByte;
      DSR(aN0, aAdN, 0);    DSR(aN1, aAdN, 1024);
      DSR(aN2, aAdN, 2048); DSR(aN3, aAdN, 3072);
      DSR(bN0, bAdN, 0);    DSR(bN1, bAdN, 1024);
      DSR(bN2, bAdN, 2048); DSR(bN3, bAdN, 3072);
    }
    if (doStage) {
      GLDS(BgT + ktS, bufS + 8192 + tid * 8);
      GLDS(BgT + rstep + ktS, bufS + 12288 + tid * 8);
    }
    __builtin_amdgcn_s_barrier();
    WAIT_LGKM(8);  // waits the 4 B(n4-7)(t) reads issued in phase 0
    __builtin_amdgcn_s_setprio(1);
    acc[0][4] = MFMA(aC0, b4, acc[0][4]);
    acc[0][5] = MFMA(aC0, b5, acc[0][5]);
    acc[0][6] = MFMA(aC0, b6, acc[0][6]);
    acc[0][7] = MFMA(aC0, b7, acc[0][7]);
    acc[1][4] = MFMA(aC1, b4, acc[1][4]);
    acc[1][5] = MFMA(aC1, b5, acc[1][5]);
    acc[1][6] = MFMA(aC1, b6, acc[1][6]);
    acc[1][7] = MFMA(aC1, b7, acc[1][7]);
    acc[2][4] = MFMA(aC2, b4, acc[2][4]);
    acc[2][5] = MFMA(aC2, b5, acc[2][5]);
    acc[2][6] = MFMA(aC2, b6, acc[2][6]);
    acc[2][7] = MFMA(aC2, b7, acc[2][7]);
    acc[3][4] = MFMA(aC3, b4, acc[3][4]);
    acc[3][5] = MFMA(aC3, b5, acc[3][5]);
    acc[3][6] = MFMA(aC3, b6, acc[3][6]);
    acc[3][7] = MFMA(aC3, b7, acc[3][7]);
    __builtin_amdgcn_s_setprio(0);
    // Counted wait: outstanding = S_{t+1}(4) + S_{t+2}(4); vmcnt(4) => t+1 resident.
    if (t < nt - 2) {
      asm volatile("s_waitcnt vmcnt(4)" ::: "memory");
    } else if (t == nt - 2) {
      asm volatile("s_waitcnt vmcnt(0)" ::: "memory");
    }
    __builtin_amdgcn_s_barrier();

    // rotate read-ahead fragments into current
    aC0 = aN0; aC1 = aN1; aC2 = aN2; aC3 = aN3;
    bC0 = bN0; bC1 = bN1; bC2 = bN2; bC3 = bN3;
    rb = rbN;
  }

  // ---- epilogue: C/D layout col = lane&15, row = (lane>>4)*4 + reg ----
  float g = gamma[0];
  int rb0 = bm * BM + wm * 64 + l4 * 4;
  int cb0 = bn * BN + wn * 128 + l15;
#pragma unroll
  for (int m = 0; m < 4; ++m) {
#pragma unroll
    for (int j = 0; j < 4; ++j) {
      int row = rb0 + m * 16 + j;
      float xr = x2[row];
      size_t ob = (size_t)row * N;
#pragma unroll
      for (int n = 0; n < 8; ++n) {
        int col = cb0 + n * 16;
        float sq = fmaxf(xr + c2[col] - 2.f * acc[m][n][j], 0.f);
        out[ob + col] = __expf(-g * __builtin_sqrtf(sq));
      }
    }
  }
}

// Correctness fallback if workspace/shape doesn't fit (slow, fp32 vector path).
__global__ __launch_bounds__(256) void rbf_naive(
    const float* __restrict__ x, const float* __restrict__ cent,
    const float* __restrict__ gamma, float* __restrict__ out, int D, int N) {
  int row = blockIdx.x;
  int col = blockIdx.y * blockDim.x + threadIdx.x;
  extern __shared__ float xs[];
  for (int i = threadIdx.x; i < D; i += blockDim.x)
    xs[i] = x[(size_t)row * D + i];
  __syncthreads();
  if (col >= N) return;
  const float* cp = cent + (size_t)col * D;
  float s = 0.f;
  for (int d = 0; d < D; ++d) {
    float df = xs[d] - cp[d];
    s += df * df;
  }
  out[(size_t)row * N + col] = __expf(-gamma[0] * __builtin_sqrtf(fmaxf(s, 0.f)));
}

extern "C" void kernel_launch(void* const* d_in, const int* in_sizes, int n_in,
                              void* d_out, int out_size, void* d_ws, size_t ws_size,
                              hipStream_t stream) {
  const float* x = (const float*)d_in[0];
  const float* cent = (const float*)d_in[1];
  const float* gamma = (const float*)d_in[2];
  float* out = (float*)d_out;

  const int D = 1024;  // feature dim per the reference
  int Brows = in_sizes[0] / D;
  int C = in_sizes[1] / D;

  size_t xb_bytes = (size_t)Brows * D * 2;
  size_t cb_bytes = (size_t)C * D * 2;
  size_t need = xb_bytes + cb_bytes + (size_t)Brows * 4 + (size_t)C * 4;
  bool can = (ws_size >= need) && (Brows % BM == 0) && (C % BN == 0) &&
             (D % BK == 0) && (D / BK >= 3);

  if (!can) {
    dim3 grid(Brows, (C + 255) / 256);
    hipLaunchKernelGGL(rbf_naive, grid, dim3(256), D * sizeof(float), stream,
                       x, cent, gamma, out, D, C);
    return;
  }

  unsigned short* xb = (unsigned short*)d_ws;
  unsigned short* cb = (unsigned short*)((char*)d_ws + xb_bytes);
  float* x2 = (float*)((char*)d_ws + xb_bytes + cb_bytes);
  float* c2 = x2 + Brows;

  hipLaunchKernelGGL(prep_rows, dim3(Brows), dim3(256), 0, stream, x, xb, x2, D);
  hipLaunchKernelGGL(prep_rows, dim3(C), dim3(256), 0, stream, cent, cb, c2, D);

  int nwg = (Brows / BM) * (C / BN);
  hipLaunchKernelGGL(rbf_gemm, dim3(nwg), dim3(512), 0, stream,
                     xb, cb, x2, c2, gamma, out, Brows, C, D);
}